// Round 2
// baseline (223.847 us; speedup 1.0000x reference)
//
#include <hip/hip_runtime.h>
#include <stdint.h>

#define BATCH   65536

typedef __bf16 bf16x8 __attribute__((ext_vector_type(8)));
typedef float  f32x16 __attribute__((ext_vector_type(16)));

__device__ __forceinline__ uint32_t f2bf1(float v) {
  uint32_t u = __float_as_uint(v);
  return (u + 0x7FFFu + ((u >> 16) & 1u)) >> 16;   // RNE bf16
}

__device__ __forceinline__ float fast_sigmoid(float x) {
  return __builtin_amdgcn_rcpf(1.0f + __expf(-x));
}
__device__ __forceinline__ float fast_tanh(float x) {
  return 1.0f - 2.0f * __builtin_amdgcn_rcpf(1.0f + __expf(2.0f * x));
}

// ---------------- prep: weights -> bf16 fragment image ----------------
// chunk index t = nb*8192 + ks*512 + kh*256 + g*64 + lane   (16B chunks, 1 MB total)
// chunk holds 8 bf16: Wcat[k = ks*32 + kh*16 + (lane>>5)*8 + i][g*256 + nb*32 + (lane&31)]
// Wcat rows 0..255 = kernel (x), 256..511 = recurrent_kernel (h).
__global__ __launch_bounds__(256) void prep_weights(
    const float* __restrict__ wk, const float* __restrict__ wr,
    uint4* __restrict__ img) {
  int t  = blockIdx.x * 256 + threadIdx.x;   // 0..65535
  int l  = t & 63;
  int g  = (t >> 6) & 3;
  int kh = (t >> 8) & 1;
  int ks = (t >> 9) & 15;
  int nb = t >> 13;
  int k0  = ks * 32 + kh * 16 + (l >> 5) * 8;
  int col = g * 256 + nb * 32 + (l & 31);
  uint32_t o[4];
#pragma unroll
  for (int p = 0; p < 4; ++p) {
    int k = k0 + p * 2;
    float s0 = (k     < 256) ? wk[(size_t)k * 1024 + col]         : wr[(size_t)(k - 256) * 1024 + col];
    float s1 = (k + 1 < 256) ? wk[(size_t)(k + 1) * 1024 + col]   : wr[(size_t)(k - 255) * 1024 + col];
    o[p] = f2bf1(s0) | (f2bf1(s1) << 16);
  }
  img[t] = make_uint4(o[0], o[1], o[2], o[3]);
}

// ---------------- fused LSTM: LDS-free, barrier-free ----------------
// block = 256 thr = 4 waves M-stacked; wave tile = 32 rows x 128 cols (4 gates x 32 units)
// grid = 4096 1-D, XCD-chunked swizzle: 8 nb-blocks of one rt land on the same XCD -> A L2-shared.
__global__ __launch_bounds__(256) void lstm_fused(
    const float* __restrict__ xp, const float* __restrict__ hp,
    const float* __restrict__ cp, const float* __restrict__ bp,
    const uint4* __restrict__ img, float* __restrict__ outp) {

  const int tid  = threadIdx.x;
  const int lane = tid & 63;
  const int wv   = tid >> 6;
  const int ln31 = lane & 31;
  const int hi32 = lane >> 5;

  // XCD-chunked bijective swizzle (4096 % 8 == 0): XCD x gets rt in [x*64,(x+1)*64),
  // nb cycles fastest -> 8 consecutive blocks on one XCD share one 256 KB A panel.
  const int orig = blockIdx.x;
  const int wg   = (orig & 7) * 512 + (orig >> 3);
  const int nb   = wg & 7;
  const int rt   = wg >> 3;

  const int row = rt * 128 + wv * 32 + ln31;
  const float* ax = xp + (size_t)row * 256 + hi32 * 8;
  const float* ah = hp + (size_t)row * 256 + hi32 * 8;
  const uint4* bb = img + (size_t)nb * 8192 + lane;

  f32x16 acc[4];
#pragma unroll
  for (int g = 0; g < 4; ++g)
#pragma unroll
    for (int i = 0; i < 16; ++i) acc[g][i] = 0.0f;

  float4 A0[4], A1[4];
  uint4  B0[8], B1[8];

  auto loadA = [&](int ks, float4* A) {
    const float* s = (ks < 8) ? (ax + ks * 32) : (ah + (ks - 8) * 32);
#pragma unroll
    for (int kh = 0; kh < 2; ++kh) {
      A[kh * 2 + 0] = *(const float4*)(s + kh * 16);
      A[kh * 2 + 1] = *(const float4*)(s + kh * 16 + 4);
    }
  };
  auto loadB = [&](int ks, uint4* B) {
    const uint4* s = bb + ks * 512;
#pragma unroll
    for (int kh = 0; kh < 2; ++kh)
#pragma unroll
      for (int g = 0; g < 4; ++g)
        B[kh * 4 + g] = s[kh * 256 + g * 64];
  };
  auto compute = [&](const float4* A, const uint4* B) {
#pragma unroll
    for (int kh = 0; kh < 2; ++kh) {
      const float4 lo = A[kh * 2 + 0], hi = A[kh * 2 + 1];
      bf16x8 af;
      af[0] = (__bf16)lo.x; af[1] = (__bf16)lo.y;
      af[2] = (__bf16)lo.z; af[3] = (__bf16)lo.w;
      af[4] = (__bf16)hi.x; af[5] = (__bf16)hi.y;
      af[6] = (__bf16)hi.z; af[7] = (__bf16)hi.w;
#pragma unroll
      for (int g = 0; g < 4; ++g) {
        bf16x8 bf = __builtin_bit_cast(bf16x8, B[kh * 4 + g]);
        acc[g] = __builtin_amdgcn_mfma_f32_32x32x16_bf16(af, bf, acc[g], 0, 0, 0);
      }
    }
  };

  // register-double-buffered, fully unrolled (all indices static), barrier-free
  loadA(0, A0);
  loadB(0, B0);
#pragma unroll
  for (int kk = 0; kk < 8; ++kk) {
    const int ks = 2 * kk;
    loadA(ks + 1, A1);
    loadB(ks + 1, B1);
    compute(A0, B0);
    if (ks + 2 < 16) {
      loadA(ks + 2, A0);
      loadB(ks + 2, B0);
    }
    compute(A1, B1);
  }

  // ---- epilogue: gates + cell update, in-register per lane ----
  const int u = nb * 32 + ln31;
  const float bi  = bp[u];
  const float bf_ = bp[256 + u];
  const float bg  = bp[512 + u];
  const float bo  = bp[768 + u];
  const int rowbase = rt * 128 + wv * 32 + 4 * hi32;
  float* outh = outp;
  float* outc = outp + (size_t)BATCH * 256;
#pragma unroll
  for (int r = 0; r < 16; ++r) {
    int orow = rowbase + (r & 3) + 8 * (r >> 2);
    size_t idx = (size_t)orow * 256 + u;
    float zi = acc[0][r] + bi;
    float zf = acc[1][r] + bf_;
    float zg = acc[2][r] + bg;
    float zo = acc[3][r] + bo;
    float iv = fast_sigmoid(zi);
    float fv = fast_sigmoid(zf);
    float gv = fast_tanh(zg);
    float ov = fast_sigmoid(zo);
    float cv = __builtin_nontemporal_load(cp + idx);
    float cn = fv * cv + iv * gv;
    float hn = ov * fast_tanh(cn);
    __builtin_nontemporal_store(hn, outh + idx);   // streaming: don't evict A/B in L2
    __builtin_nontemporal_store(cn, outc + idx);
  }
}

extern "C" void kernel_launch(void* const* d_in, const int* in_sizes, int n_in,
                              void* d_out, int out_size, void* d_ws, size_t ws_size,
                              hipStream_t stream) {
  const float* x  = (const float*)d_in[0];
  const float* h  = (const float*)d_in[1];
  const float* c  = (const float*)d_in[2];
  const float* wk = (const float*)d_in[3];
  const float* wr = (const float*)d_in[4];
  const float* b  = (const float*)d_in[5];
  prep_weights<<<256, 256, 0, stream>>>(wk, wr, (uint4*)d_ws);   // 1 MB bf16 fragment image
  lstm_fused<<<4096, 256, 0, stream>>>(x, h, c, b,
                                       (const uint4*)d_ws, (float*)d_out);
}

// Round 3
// 142.898 us; speedup vs baseline: 1.5665x; 1.5665x over previous
//
#include <hip/hip_runtime.h>
#include <stdint.h>

#define BATCH   65536
#define BM      128
#define NSTEP   16

typedef __bf16 bf16x8 __attribute__((ext_vector_type(8)));
typedef float  f32x16 __attribute__((ext_vector_type(16)));

__device__ __forceinline__ uint32_t f2bf1(float v) {
  uint32_t u = __float_as_uint(v);
  return (u + 0x7FFFu + ((u >> 16) & 1u)) >> 16;   // RNE bf16
}

__device__ __forceinline__ uint32_t cvt_pk_bf16(float lo, float hi) {
  uint32_t r;
  asm volatile("v_cvt_pk_bf16_f32 %0, %1, %2" : "=v"(r) : "v"(lo), "v"(hi));
  return r;
}

__device__ __forceinline__ float fast_sigmoid(float x) {
  return __builtin_amdgcn_rcpf(1.0f + __expf(-x));
}
__device__ __forceinline__ float fast_tanh(float x) {
  return 1.0f - 2.0f * __builtin_amdgcn_rcpf(1.0f + __expf(2.0f * x));
}

// ---------------- prep: weights -> gathered/transposed/swizzled bf16 image ----------------
// (identical to round-1 layout, which passed)
__global__ __launch_bounds__(256) void prep_weights(
    const float* __restrict__ wk, const float* __restrict__ wr,
    uint4* __restrict__ wsw) {
  int t    = blockIdx.x * 256 + threadIdx.x;   // 0..65535
  int slot = t & 3;
  int n    = (t >> 2) & 127;
  int ks   = (t >> 9) & 15;
  int nb   = t >> 13;
  int cch  = slot ^ ((n >> 1) & 3);
  int k0   = ks * 32 + cch * 8;
  int col  = (n >> 5) * 256 + nb * 32 + (n & 31);
  uint32_t o[4];
#pragma unroll
  for (int p = 0; p < 4; ++p) {
    int k = k0 + p * 2;
    const float* s0 = (k < 256) ? (wk + (size_t)k * 1024 + col)
                                : (wr + (size_t)(k - 256) * 1024 + col);
    const float* s1 = (k + 1 < 256) ? (wk + (size_t)(k + 1) * 1024 + col)
                                    : (wr + (size_t)(k - 255) * 1024 + col);
    o[p] = f2bf1(*s0) | (f2bf1(*s1) << 16);
  }
  wsw[t] = make_uint4(o[0], o[1], o[2], o[3]);
}

// ---------------- fused LSTM GEMM (r1 pipeline + XCD-chunked swizzle) ----------------
// block: 128 batch rows x (4 gates x 32 units). 4 waves M-stacked, wave = 32x128.
// grid 4096 1-D; swizzle puts the 8 nb-blocks of one rt consecutively on ONE XCD,
// so the 256 KB A panel (x,h rows) is HBM-fetched once and L2-served 7 times.
__global__ __launch_bounds__(256) void lstm_fused(
    const float* __restrict__ xp, const float* __restrict__ hp,
    const float* __restrict__ cp, const float* __restrict__ bp,
    const uint32_t* __restrict__ wsw, float* __restrict__ outp) {

  __shared__ __align__(16) char smem[32768];
  // A: [0,8192) buf0, [8192,16384) buf1 ; B: [16384,24576) buf0, [24576,32768) buf1

  const int tid  = threadIdx.x;
  const int lane = tid & 63;
  const int wv   = tid >> 6;
  const int ln31 = lane & 31;
  const int hi32 = lane >> 5;

  // XCD-chunked bijective swizzle (4096 % 8 == 0): XCD x gets wg in [x*512,(x+1)*512),
  // nb cycling fastest -> the 8 sharers of one A panel are dispatched back-to-back.
  const int orig = blockIdx.x;
  const int wg   = (orig & 7) * 512 + (orig >> 3);
  const int nb   = wg & 7;
  const int rt   = wg >> 3;

  // ---- A staging constants (reg-stage fp32 -> bf16, swizzled ds_write) ----
  const int arow0 = tid >> 3;          // 0..31
  const int ac4   = tid & 7;           // which float4 of the 32-k strip
  const float* xsrc = xp + (size_t)(rt * BM + arow0) * 256 + ac4 * 4;
  const float* hsrc = hp + (size_t)(rt * BM + arow0) * 256 + ac4 * 4;
  const int aswz_w = (arow0 >> 1) & 3;  // j-invariant since rows step by 32
  int awoff[4];
#pragma unroll
  for (int j = 0; j < 4; ++j) {
    int r = arow0 + 32 * j;
    awoff[j] = r * 64 + (((ac4 >> 1) ^ aswz_w) << 4) + ((ac4 & 1) << 3);
  }

  // ---- B staging: wave wv DMA-copies image chunks 2wv, 2wv+1 (1KB each) ----
  const uint32_t* bsrc0 = wsw + (size_t)nb * 16 * 2048 + (2 * wv) * 256 + lane * 4;

  // ---- compute-side LDS read offsets (loop-invariant) ----
  const int amr    = wv * 32 + ln31;           // A row for this wave
  const int aswz_r = (amr >> 1) & 3;
  int aro[2], bro[8];
#pragma unroll
  for (int hh = 0; hh < 2; ++hh) {
    aro[hh] = amr * 64 + (((hh * 2 + hi32) ^ aswz_r) << 4);
#pragma unroll
    for (int g = 0; g < 4; ++g) {
      int n = g * 32 + ln31;
      bro[g * 2 + hh] = n * 64 + (((hh * 2 + hi32) ^ ((n >> 1) & 3)) << 4);
    }
  }

  f32x16 acc[4];
#pragma unroll
  for (int g = 0; g < 4; ++g)
#pragma unroll
    for (int i = 0; i < 16; ++i) acc[g][i] = 0.0f;

  float4 areg[4];

  auto load_a = [&](int ks) {
    const float* s = (ks < 8) ? (xsrc + ks * 32) : (hsrc + (ks - 8) * 32);
#pragma unroll
    for (int j = 0; j < 4; ++j)
      areg[j] = *(const float4*)(s + (size_t)j * 32 * 256);
  };
  auto write_a = [&](int buf) {
    char* base = smem + buf * 8192;
#pragma unroll
    for (int j = 0; j < 4; ++j) {
      uint32_t p0 = cvt_pk_bf16(areg[j].x, areg[j].y);
      uint32_t p1 = cvt_pk_bf16(areg[j].z, areg[j].w);
      *(uint2*)(base + awoff[j]) = make_uint2(p0, p1);
    }
  };
  auto glds_b = [&](int ks, int buf) {
    const uint32_t* src = bsrc0 + (size_t)ks * 2048;
    char* dst = smem + 16384 + buf * 8192 + (2 * wv) * 1024;
    __builtin_amdgcn_global_load_lds(
        (const __attribute__((address_space(1))) uint32_t*)src,
        (__attribute__((address_space(3))) uint32_t*)dst, 16, 0, 0);
    __builtin_amdgcn_global_load_lds(
        (const __attribute__((address_space(1))) uint32_t*)(src + 256),
        (__attribute__((address_space(3))) uint32_t*)(dst + 1024), 16, 0, 0);
  };
  auto compute = [&](int buf) {
    const char* ab = smem + buf * 8192;
    const char* bb = smem + 16384 + buf * 8192;
#pragma unroll
    for (int hh = 0; hh < 2; ++hh) {
      bf16x8 af = *(const bf16x8*)(ab + aro[hh]);
#pragma unroll
      for (int g = 0; g < 4; ++g) {
        bf16x8 bfr = *(const bf16x8*)(bb + bro[g * 2 + hh]);
        acc[g] = __builtin_amdgcn_mfma_f32_32x32x16_bf16(af, bfr, acc[g], 0, 0, 0);
      }
    }
  };

  // prologue: stage K-step 0
  load_a(0);
  write_a(0);
  glds_b(0, 0);
  __syncthreads();

#pragma unroll 2
  for (int ks = 0; ks < NSTEP; ++ks) {
    const int cur = ks & 1;
    if (ks < NSTEP - 1) {
      glds_b(ks + 1, cur ^ 1);   // DMA next B tile (overlaps compute)
      load_a(ks + 1);            // next A tile into regs (overlaps compute)
    }
    compute(cur);
    if (ks < NSTEP - 1) write_a(cur ^ 1);
    __syncthreads();             // one barrier per K-step
  }

  // ---- epilogue: gates + cell update, in-register; nontemporal streaming ----
  const int u = nb * 32 + ln31;
  const float bi  = bp[u];
  const float bf_ = bp[256 + u];
  const float bg  = bp[512 + u];
  const float bo  = bp[768 + u];
  const int rowbase = rt * BM + wv * 32 + 4 * hi32;
  float* outh = outp;
  float* outc = outp + (size_t)BATCH * 256;
#pragma unroll
  for (int r = 0; r < 16; ++r) {
    int row = rowbase + (r & 3) + 8 * (r >> 2);
    size_t idx = (size_t)row * 256 + u;
    float zi = acc[0][r] + bi;
    float zf = acc[1][r] + bf_;
    float zg = acc[2][r] + bg;
    float zo = acc[3][r] + bo;
    float iv = fast_sigmoid(zi);
    float fv = fast_sigmoid(zf);
    float gv = fast_tanh(zg);
    float ov = fast_sigmoid(zo);
    float cv = __builtin_nontemporal_load(cp + idx);
    float cn = fv * cv + iv * gv;
    float hn = ov * fast_tanh(cn);
    __builtin_nontemporal_store(hn, outh + idx);   // don't evict L3-resident inputs
    __builtin_nontemporal_store(cn, outc + idx);
  }
}

extern "C" void kernel_launch(void* const* d_in, const int* in_sizes, int n_in,
                              void* d_out, int out_size, void* d_ws, size_t ws_size,
                              hipStream_t stream) {
  const float* x  = (const float*)d_in[0];
  const float* h  = (const float*)d_in[1];
  const float* c  = (const float*)d_in[2];
  const float* wk = (const float*)d_in[3];
  const float* wr = (const float*)d_in[4];
  const float* b  = (const float*)d_in[5];
  prep_weights<<<256, 256, 0, stream>>>(wk, wr, (uint4*)d_ws);   // 1 MB bf16 image
  lstm_fused<<<4096, 256, 0, stream>>>(x, h, c, b,
                                       (const uint32_t*)d_ws, (float*)d_out);
}